// Round 4
// baseline (144.561 us; speedup 1.0000x reference)
//
#include <hip/hip_runtime.h>
#include <hip/hip_bf16.h>

#define B_TOT 16384
#define C_CH  64
#define F_IN  128
#define H_HID 128
#define ROWS  512      // rows per block; 4 waves x 8 sub-chunks x 16 rows
#define NSUB  8        // sub-chunks per wave

using f32x4  = __attribute__((ext_vector_type(4))) float;
using bf16x8 = __attribute__((ext_vector_type(8))) short;

__device__ inline unsigned pack2(float a, float b) {
    unsigned short lo = __builtin_bit_cast(unsigned short, __float2bfloat16(a));
    unsigned short hi = __builtin_bit_cast(unsigned short, __float2bfloat16(b));
    return (unsigned)lo | ((unsigned)hi << 16);
}

// issue the 8 float4 loads for one 16-row sub-chunk (8 KB/wave in flight)
__device__ inline void load_sub(const float* __restrict__ X, int rbase, int c,
                                int l15, int lg, float4 (&r)[8]) {
    const float* xb = X + ((size_t)(rbase + l15) * C_CH + c) * F_IN + lg * 8;
    #pragma unroll
    for (int ks = 0; ks < 4; ++ks) {
        r[ks * 2]     = *reinterpret_cast<const float4*>(xb + ks * 32);
        r[ks * 2 + 1] = *reinterpret_cast<const float4*>(xb + ks * 32 + 4);
    }
}

__device__ inline void compute_sub(const char* ws, const float4 (&r)[8],
                                   const float (&w2v)[8], const float (&b1v)[8],
                                   float b2c, int rbase, int l15, int lg,
                                   float* __restrict__ out)
{
    f32x4 acc[8];
    #pragma unroll
    for (int nf = 0; nf < 8; ++nf) acc[nf] = f32x4{0.f, 0.f, 0.f, 0.f};

    #pragma unroll
    for (int ks = 0; ks < 4; ++ks) {
        const int kbyte = ks * 64 + lg * 16;
        float4 r0 = r[ks * 2], r1 = r[ks * 2 + 1];
        uint4 pa;
        pa.x = pack2(r0.x, r0.y);
        pa.y = pack2(r0.z, r0.w);
        pa.z = pack2(r1.x, r1.y);
        pa.w = pack2(r1.z, r1.w);
        bf16x8 a = __builtin_bit_cast(bf16x8, pa);
        #pragma unroll
        for (int nf = 0; nf < 8; ++nf) {
            int n = nf * 16 + l15;
            bf16x8 b = *reinterpret_cast<const bf16x8*>(
                ws + n * 256 + (kbyte ^ ((n & 7) << 4)));
            acc[nf] = __builtin_amdgcn_mfma_f32_16x16x32_bf16(a, b, acc[nf], 0, 0, 0);
        }
    }

    // relu(+b1), dot W2, 16-lane col reduce, one atomic per row
    float part[4] = {0.f, 0.f, 0.f, 0.f};
    #pragma unroll
    for (int nf = 0; nf < 8; ++nf)
        #pragma unroll
        for (int j = 0; j < 4; ++j)
            part[j] += fmaxf(acc[nf][j] + b1v[nf], 0.f) * w2v[nf];
    #pragma unroll
    for (int off = 8; off >= 1; off >>= 1)
        #pragma unroll
        for (int j = 0; j < 4; ++j)
            part[j] += __shfl_xor(part[j], off, 64);
    if (l15 == 0) {
        int row = rbase + lg * 4;
        #pragma unroll
        for (int j = 0; j < 4; ++j)
            atomicAdd(&out[row + j], part[j] + b2c);
    }
}

__global__ __launch_bounds__(256, 2)
void fused_mlp_kernel(const float* __restrict__ X,
                      const float* __restrict__ W1,
                      const float* __restrict__ b1,
                      const float* __restrict__ W2,
                      const float* __restrict__ b2,
                      float* __restrict__ out)
{
    __shared__ short Ws[H_HID * F_IN];   // W1_c bf16 [n][k], XOR-swizzled

    const int t    = threadIdx.x;
    const int lane = t & 63;
    const int wave = t >> 6;
    // channel-major grid: co-resident blocks cover ALL channels of consecutive
    // rowtiles -> near-sequential DRAM stream; XCD = c%8 -> W1_c L2-pinned.
    const int c    = blockIdx.x;
    const int m0   = blockIdx.y * ROWS;

    char* ws = reinterpret_cast<char*>(Ws);

    // ---- stage W1_c transposed to [n][k]: coalesced along n ----
    {
        const int n  = t & 127;
        const int kh = (t >> 7) * 64;
        const float* wbase = W1 + (size_t)c * F_IN * H_HID + n;
        #pragma unroll
        for (int kk = 0; kk < 64; kk += 8) {
            float f[8];
            #pragma unroll
            for (int j = 0; j < 8; ++j)
                f[j] = wbase[(size_t)(kh + kk + j) * H_HID];
            uint4 p;
            p.x = pack2(f[0], f[1]);
            p.y = pack2(f[2], f[3]);
            p.z = pack2(f[4], f[5]);
            p.w = pack2(f[6], f[7]);
            int byte = ((kh + kk) * 2) ^ ((n & 7) << 4);
            *reinterpret_cast<uint4*>(ws + n * 256 + byte) = p;
        }
    }

    const int l15 = lane & 15;
    const int lg  = lane >> 4;

    float w2v[8], b1v[8];
    #pragma unroll
    for (int nf = 0; nf < 8; ++nf) {
        w2v[nf] = W2[c * H_HID + nf * 16 + l15];
        b1v[nf] = b1[c * H_HID + nf * 16 + l15];
    }
    const float b2c = b2[c];

    __syncthreads();

    // ---- depth-2 software pipeline: 3 rotating reg buffers, full unroll so
    // all buffer indices are compile-time constants (no scratch) ----
    float4 buf[3][8];
    load_sub(X, m0 + (0 * 4 + wave) * 16, c, l15, lg, buf[0]);
    load_sub(X, m0 + (1 * 4 + wave) * 16, c, l15, lg, buf[1]);

    #pragma unroll
    for (int sc = 0; sc < NSUB; ++sc) {
        if (sc + 2 < NSUB)
            load_sub(X, m0 + ((sc + 2) * 4 + wave) * 16, c, l15, lg,
                     buf[(sc + 2) % 3]);
        compute_sub(ws, buf[sc % 3], w2v, b1v, b2c,
                    m0 + (sc * 4 + wave) * 16, l15, lg, out);
    }
}

extern "C" void kernel_launch(void* const* d_in, const int* in_sizes, int n_in,
                              void* d_out, int out_size, void* d_ws, size_t ws_size,
                              hipStream_t stream) {
    const float* X  = (const float*)d_in[0];   // [B, C, F]
    const float* W1 = (const float*)d_in[1];   // [C, F, H]
    const float* b1 = (const float*)d_in[2];   // [C, H]
    const float* W2 = (const float*)d_in[3];   // [C, H]
    const float* b2 = (const float*)d_in[4];   // [C]
    float* out = (float*)d_out;                // [B]

    // atomics accumulate into out -> must zero it every call (d_out is poisoned)
    hipMemsetAsync(out, 0, (size_t)out_size * sizeof(float), stream);

    dim3 grid(C_CH, B_TOT / ROWS);   // channel-major
    fused_mlp_kernel<<<grid, dim3(256), 0, stream>>>(X, W1, b1, W2, b2, out);
}

// Round 5
// 123.967 us; speedup vs baseline: 1.1661x; 1.1661x over previous
//
#include <hip/hip_runtime.h>
#include <hip/hip_bf16.h>

#define B_TOT 16384
#define C_CH  64
#define F_IN  128
#define H_HID 128
#define ROWS  512      // rows per block; 4 waves x 8 sub-chunks x 16 rows
#define NSUB  8        // sub-chunks per wave

using f32x4  = __attribute__((ext_vector_type(4))) float;
using bf16x8 = __attribute__((ext_vector_type(8))) short;

__device__ inline unsigned pack2(float a, float b) {
    unsigned short lo = __builtin_bit_cast(unsigned short, __float2bfloat16(a));
    unsigned short hi = __builtin_bit_cast(unsigned short, __float2bfloat16(b));
    return (unsigned)lo | ((unsigned)hi << 16);
}

// issue the 8 float4 loads for one 16-row sub-chunk (8 KB/wave in flight)
__device__ inline void load_sub(const float* __restrict__ X, int rbase, int c,
                                int l15, int lg, float4 (&r)[8]) {
    const float* xb = X + ((size_t)(rbase + l15) * C_CH + c) * F_IN + lg * 8;
    #pragma unroll
    for (int ks = 0; ks < 4; ++ks) {
        r[ks * 2]     = *reinterpret_cast<const float4*>(xb + ks * 32);
        r[ks * 2 + 1] = *reinterpret_cast<const float4*>(xb + ks * 32 + 4);
    }
}

__device__ inline void compute_sub(const char* ws, const float4 (&r)[8],
                                   const float (&w2v)[8], const float (&b1v)[8],
                                   float b2c, int rbase, int l15, int lg,
                                   float* __restrict__ out)
{
    f32x4 acc[8];
    #pragma unroll
    for (int nf = 0; nf < 8; ++nf) acc[nf] = f32x4{0.f, 0.f, 0.f, 0.f};

    #pragma unroll
    for (int ks = 0; ks < 4; ++ks) {
        const int kbyte = ks * 64 + lg * 16;
        float4 r0 = r[ks * 2], r1 = r[ks * 2 + 1];
        uint4 pa;
        pa.x = pack2(r0.x, r0.y);
        pa.y = pack2(r0.z, r0.w);
        pa.z = pack2(r1.x, r1.y);
        pa.w = pack2(r1.z, r1.w);
        bf16x8 a = __builtin_bit_cast(bf16x8, pa);
        #pragma unroll
        for (int nf = 0; nf < 8; ++nf) {
            int n = nf * 16 + l15;
            bf16x8 b = *reinterpret_cast<const bf16x8*>(
                ws + n * 256 + (kbyte ^ ((n & 7) << 4)));
            acc[nf] = __builtin_amdgcn_mfma_f32_16x16x32_bf16(a, b, acc[nf], 0, 0, 0);
        }
    }

    // relu(+b1), dot W2, 16-lane col reduce, one atomic per row
    float part[4] = {0.f, 0.f, 0.f, 0.f};
    #pragma unroll
    for (int nf = 0; nf < 8; ++nf)
        #pragma unroll
        for (int j = 0; j < 4; ++j)
            part[j] += fmaxf(acc[nf][j] + b1v[nf], 0.f) * w2v[nf];
    #pragma unroll
    for (int off = 8; off >= 1; off >>= 1)
        #pragma unroll
        for (int j = 0; j < 4; ++j)
            part[j] += __shfl_xor(part[j], off, 64);
    if (l15 == 0) {
        int row = rbase + lg * 4;
        #pragma unroll
        for (int j = 0; j < 4; ++j)
            atomicAdd(&out[row + j], part[j] + b2c);
    }
}

__global__ __launch_bounds__(256, 2)
void fused_mlp_kernel(const float* __restrict__ X,
                      const float* __restrict__ W1,
                      const float* __restrict__ b1,
                      const float* __restrict__ W2,
                      const float* __restrict__ b2,
                      float* __restrict__ out)
{
    __shared__ short Ws[H_HID * F_IN];   // W1_c bf16 [n][k], XOR-swizzled

    const int t    = threadIdx.x;
    const int lane = t & 63;
    const int wave = t >> 6;

    // XCD-contiguous swizzle: XCD = id%8 (round-robin). Each XCD gets row
    // stripes y = yl*8 + k for ALL 64 channels -> co-resident blocks on one
    // XCD consume a CONTIGUOUS 16MB X span (dense DRAM pages), instead of
    // 8-of-64 channels' 512B chunks scattered across 8 regions (r3: ~1/8
    // page density, 4.3 TB/s). W1 loses XCD-pinning but is L3-resident (4MB).
    const int id = blockIdx.x;           // 0..2047
    const int k  = id & 7;               // XCD
    const int q  = id >> 3;
    const int c  = q & 63;               // channel (fast within XCD timeline)
    const int yl = q >> 6;               // 0..3
    const int m0 = (yl * 8 + k) * ROWS;

    char* ws = reinterpret_cast<char*>(Ws);

    // ---- stage W1_c transposed to [n][k]: coalesced along n ----
    {
        const int n  = t & 127;
        const int kh = (t >> 7) * 64;
        const float* wbase = W1 + (size_t)c * F_IN * H_HID + n;
        #pragma unroll
        for (int kk = 0; kk < 64; kk += 8) {
            float f[8];
            #pragma unroll
            for (int j = 0; j < 8; ++j)
                f[j] = wbase[(size_t)(kh + kk + j) * H_HID];
            uint4 p;
            p.x = pack2(f[0], f[1]);
            p.y = pack2(f[2], f[3]);
            p.z = pack2(f[4], f[5]);
            p.w = pack2(f[6], f[7]);
            int byte = ((kh + kk) * 2) ^ ((n & 7) << 4);
            *reinterpret_cast<uint4*>(ws + n * 256 + byte) = p;
        }
    }

    const int l15 = lane & 15;
    const int lg  = lane >> 4;

    float w2v[8], b1v[8];
    #pragma unroll
    for (int nf = 0; nf < 8; ++nf) {
        w2v[nf] = W2[c * H_HID + nf * 16 + l15];
        b1v[nf] = b1[c * H_HID + nf * 16 + l15];
    }
    const float b2c = b2[c];

    __syncthreads();

    // ---- depth-1 ping-pong (r3 structure; depth-2 spilled in r4) ----
    float4 rA[8], rB[8];
    load_sub(X, m0 + wave * 16, c, l15, lg, rA);

    #pragma unroll 1
    for (int sc = 0; sc < NSUB; sc += 2) {
        const int rbA = m0 + (sc * 4 + wave) * 16;
        const int rbB = m0 + ((sc + 1) * 4 + wave) * 16;
        load_sub(X, rbB, c, l15, lg, rB);                 // prefetch sc+1
        compute_sub(ws, rA, w2v, b1v, b2c, rbA, l15, lg, out);
        if (sc + 2 < NSUB)
            load_sub(X, m0 + ((sc + 2) * 4 + wave) * 16, c, l15, lg, rA);
        compute_sub(ws, rB, w2v, b1v, b2c, rbB, l15, lg, out);
    }
}

extern "C" void kernel_launch(void* const* d_in, const int* in_sizes, int n_in,
                              void* d_out, int out_size, void* d_ws, size_t ws_size,
                              hipStream_t stream) {
    const float* X  = (const float*)d_in[0];   // [B, C, F]
    const float* W1 = (const float*)d_in[1];   // [C, F, H]
    const float* b1 = (const float*)d_in[2];   // [C, H]
    const float* W2 = (const float*)d_in[3];   // [C, H]
    const float* b2 = (const float*)d_in[4];   // [C]
    float* out = (float*)d_out;                // [B]

    // atomics accumulate into out -> must zero it every call (d_out is poisoned)
    hipMemsetAsync(out, 0, (size_t)out_size * sizeof(float), stream);

    fused_mlp_kernel<<<dim3(2048), dim3(256), 0, stream>>>(X, W1, b1, W2, b2, out);
}